// Round 17
// baseline (345.030 us; speedup 1.0000x reference)
//
#include <hip/hip_runtime.h>
#include <math.h>

#define T_SEQ 2048
#define D_MODEL 512
#define H_HEADS 8
#define HD 64
#define NCH 32      // number of chunks
#define CSZ 64      // chunk size  (NCH*CSZ == T_SEQ)
#define CAP 192     // max gathered critical entries per row (generic count = 103)

// order-preserving float<->u32 key transforms
__device__ __forceinline__ unsigned f2k(float f) {
    unsigned u = __float_as_uint(f);
    return (u & 0x80000000u) ? ~u : (u | 0x80000000u);
}
__device__ __forceinline__ float k2f(unsigned k) {
    unsigned u = (k & 0x80000000u) ? (k & 0x7fffffffu) : ~k;
    return __uint_as_float(u);
}

// ---------------- K1: QKV projection (x @ W.T + b), head-major store + phi ----------------
// grid (32, 8, 3), block 256. Transposed LDS: As[kk][row], stride 68 (16B-aligned b128 reads).
__global__ __launch_bounds__(256) void proj_qkv_kernel(
    const float* __restrict__ x,
    const float* __restrict__ wq, const float* __restrict__ bq,
    const float* __restrict__ wk, const float* __restrict__ bk,
    const float* __restrict__ wv, const float* __restrict__ bv,
    float* __restrict__ qh, float* __restrict__ kh, float* __restrict__ vh,
    float* __restrict__ qf, float* __restrict__ kf)
{
    const int which = blockIdx.z;
    const float* W    = (which == 0) ? wq : (which == 1) ? wk : wv;
    const float* bias = (which == 0) ? bq : (which == 1) ? bk : bv;
    float* outh = (which == 0) ? qh : (which == 1) ? kh : vh;
    float* outf = (which == 0) ? qf : (which == 1) ? kf : nullptr;

    __shared__ float As[32][68];
    __shared__ float Bs[32][68];
    const int tid = threadIdx.x;
    const int m0 = blockIdx.x * 64;
    const int n0 = blockIdx.y * 64;
    const int rb = (tid >> 4) * 4;
    const int cb = (tid & 15) * 4;

    float acc[4][4] = {};
    for (int k0 = 0; k0 < D_MODEL; k0 += 32) {
        for (int l = 0; l < 2; ++l) {
            int p = tid + l * 256;          // 0..511 float4 slots (64 rows x 8)
            int row = p >> 3;
            int c4 = (p & 7) * 4;
            float4 av = *(const float4*)(x + (size_t)(m0 + row) * D_MODEL + k0 + c4);
            As[c4 + 0][row] = av.x; As[c4 + 1][row] = av.y;
            As[c4 + 2][row] = av.z; As[c4 + 3][row] = av.w;
            float4 wv4 = *(const float4*)(W + (size_t)(n0 + row) * D_MODEL + k0 + c4);
            Bs[c4 + 0][row] = wv4.x; Bs[c4 + 1][row] = wv4.y;
            Bs[c4 + 2][row] = wv4.z; Bs[c4 + 3][row] = wv4.w;
        }
        __syncthreads();
        #pragma unroll
        for (int kk = 0; kk < 32; ++kk) {
            float4 ar = *(const float4*)&As[kk][rb];
            float4 br = *(const float4*)&Bs[kk][cb];
            float arr[4] = {ar.x, ar.y, ar.z, ar.w};
            float brr[4] = {br.x, br.y, br.z, br.w};
            #pragma unroll
            for (int i = 0; i < 4; ++i)
                #pragma unroll
                for (int j = 0; j < 4; ++j)
                    acc[i][j] = fmaf(arr[i], brr[j], acc[i][j]);
        }
        __syncthreads();
    }
    #pragma unroll
    for (int i = 0; i < 4; ++i) {
        int m = m0 + rb + i;
        #pragma unroll
        for (int j = 0; j < 4; ++j) {
            int n = n0 + cb + j;
            float v = acc[i][j] + bias[n];
            int h = n >> 6, d = n & 63;
            size_t idx = ((size_t)(h * T_SEQ) + m) * HD + d;
            outh[idx] = v;
            if (outf) outf[idx] = (v > 0.f) ? (v + 1.f) : __expf(v);  // elu+1
        }
    }
}

// ---------------- K6: output projection (att @ wo.T + bo) ----------------
// grid (32, 8), block 256. Transposed LDS.
__global__ __launch_bounds__(256) void out_proj_kernel(
    const float* __restrict__ att, const float* __restrict__ wo,
    const float* __restrict__ bo, float* __restrict__ out)
{
    __shared__ float As[32][68];
    __shared__ float Bs[32][68];
    const int tid = threadIdx.x;
    const int m0 = blockIdx.x * 64;
    const int n0 = blockIdx.y * 64;
    const int rb = (tid >> 4) * 4;
    const int cb = (tid & 15) * 4;

    float acc[4][4] = {};
    for (int k0 = 0; k0 < D_MODEL; k0 += 32) {
        for (int l = 0; l < 2; ++l) {
            int p = tid + l * 256;
            int row = p >> 3;
            int c4 = (p & 7) * 4;
            float4 av = *(const float4*)(att + (size_t)(m0 + row) * D_MODEL + k0 + c4);
            As[c4 + 0][row] = av.x; As[c4 + 1][row] = av.y;
            As[c4 + 2][row] = av.z; As[c4 + 3][row] = av.w;
            float4 wv4 = *(const float4*)(wo + (size_t)(n0 + row) * D_MODEL + k0 + c4);
            Bs[c4 + 0][row] = wv4.x; Bs[c4 + 1][row] = wv4.y;
            Bs[c4 + 2][row] = wv4.z; Bs[c4 + 3][row] = wv4.w;
        }
        __syncthreads();
        #pragma unroll
        for (int kk = 0; kk < 32; ++kk) {
            float4 ar = *(const float4*)&As[kk][rb];
            float4 br = *(const float4*)&Bs[kk][cb];
            float arr[4] = {ar.x, ar.y, ar.z, ar.w};
            float brr[4] = {br.x, br.y, br.z, br.w};
            #pragma unroll
            for (int i = 0; i < 4; ++i)
                #pragma unroll
                for (int j = 0; j < 4; ++j)
                    acc[i][j] = fmaf(arr[i], brr[j], acc[i][j]);
        }
        __syncthreads();
    }
    #pragma unroll
    for (int i = 0; i < 4; ++i) {
        int m = m0 + rb + i;
        #pragma unroll
        for (int j = 0; j < 4; ++j) {
            int n = n0 + cb + j;
            out[(size_t)m * D_MODEL + n] = acc[i][j] + bo[n];
        }
    }
}

// ---------------- K2a: S = Q K^T / 8, per head, 128x64 tiles ----------------
// grid (32 jtile, 16 ttile, 8 head), block 256. Transposed LDS, 8x4 acc/thread.
__global__ __launch_bounds__(256) void qk_gemm_kernel(
    const float* __restrict__ qh, const float* __restrict__ kh, float* __restrict__ S)
{
    __shared__ float As[64][132];  // As[kk][t-row 0..127]
    __shared__ float Bs[64][68];   // Bs[kk][j-col 0..63]
    const int tid = threadIdx.x;
    const int n0 = blockIdx.x * 64;    // key index j
    const int m0 = blockIdx.y * 128;   // query index t
    const int h  = blockIdx.z;
    const float* qb = qh + (size_t)h * T_SEQ * HD;
    const float* kb = kh + (size_t)h * T_SEQ * HD;

    #pragma unroll
    for (int l = 0; l < 8; ++l) {
        int p = tid + l * 256;            // 2048 float4 = 128 rows x 16
        int row = p >> 4, c4 = (p & 15) * 4;
        float4 a = *(const float4*)(qb + (size_t)(m0 + row) * HD + c4);
        As[c4 + 0][row] = a.x; As[c4 + 1][row] = a.y;
        As[c4 + 2][row] = a.z; As[c4 + 3][row] = a.w;
    }
    #pragma unroll
    for (int l = 0; l < 4; ++l) {
        int p = tid + l * 256;            // 1024 float4 = 64 rows x 16
        int row = p >> 4, c4 = (p & 15) * 4;
        float4 b = *(const float4*)(kb + (size_t)(n0 + row) * HD + c4);
        Bs[c4 + 0][row] = b.x; Bs[c4 + 1][row] = b.y;
        Bs[c4 + 2][row] = b.z; Bs[c4 + 3][row] = b.w;
    }
    __syncthreads();

    const int rb = (tid >> 4) * 8;
    const int cb = (tid & 15) * 4;
    float acc[8][4] = {};
    #pragma unroll 8
    for (int kk = 0; kk < HD; ++kk) {
        float4 a0 = *(const float4*)&As[kk][rb];
        float4 a1 = *(const float4*)&As[kk][rb + 4];
        float4 br = *(const float4*)&Bs[kk][cb];
        float arr[8] = {a0.x, a0.y, a0.z, a0.w, a1.x, a1.y, a1.z, a1.w};
        float brr[4] = {br.x, br.y, br.z, br.w};
        #pragma unroll
        for (int i = 0; i < 8; ++i)
            #pragma unroll
            for (int j = 0; j < 4; ++j)
                acc[i][j] = fmaf(arr[i], brr[j], acc[i][j]);
    }
    #pragma unroll
    for (int i = 0; i < 8; ++i) {
        float4 o;
        o.x = acc[i][0] * 0.125f; o.y = acc[i][1] * 0.125f;
        o.z = acc[i][2] * 0.125f; o.w = acc[i][3] * 0.125f;
        *(float4*)(S + ((size_t)h * T_SEQ + m0 + rb + i) * T_SEQ + n0 + cb) = o;
    }
}

// ---------------- K2b: BALLOT-BISECTION select + FUSED critical gather; WRITES att ----------------
// grid (T_SEQ, 8), block 64 (one wave per block).
// kth_R = largest v with count(k >= v) >= N-R, found by 32-step bisection where
// count() uses v_cmp + __ballot + popc -- ZERO LDS/DS-pipe traffic (the old LDS
// histogram atomics serialized on the per-CU DS pipe and were the bottleneck).
// kth values are bit-identical to the radix version -> identical output.
// LDS holds only the compacted (w,j) list for the gather.
__global__ __launch_bounds__(64, 8) void select_kernel(
    const float* __restrict__ S, const float* __restrict__ vh,
    float* __restrict__ att, float* __restrict__ marg)
{
    const int h = blockIdx.y;
    const int lane = threadIdx.x;
    const int t = blockIdx.x;
    __shared__ float2 list[CAP];

    const float* srow = S + ((size_t)h * T_SEQ + t) * T_SEQ;
    unsigned kr[32];
    unsigned mx = 0u;
    #pragma unroll
    for (int u = 0; u < 8; ++u) {
        float4 f = *(const float4*)(srow + (size_t)(lane + u * 64) * 4);
        kr[u * 4 + 0] = f2k(f.x); kr[u * 4 + 1] = f2k(f.y);
        kr[u * 4 + 2] = f2k(f.z); kr[u * 4 + 3] = f2k(f.w);
        mx = max(mx, max(max(kr[u * 4 + 0], kr[u * 4 + 1]), max(kr[u * 4 + 2], kr[u * 4 + 3])));
    }
    #pragma unroll
    for (int off = 32; off > 0; off >>= 1)
        mx = max(mx, (unsigned)__shfl_xor(mx, off));

    // ---- ballot-bisection for ranks 204 and 1944 (0-based); wave-uniform ----
    unsigned kth0 = 0u, kth1 = 0u;
    for (int b = 31; b >= 0; --b) {
        const unsigned bit = 1u << b;
        const unsigned t0 = kth0 | bit, t1 = kth1 | bit;
        unsigned c0 = 0u, c1 = 0u;
        #pragma unroll
        for (int u = 0; u < 32; ++u) {
            c0 += (unsigned)__popcll(__ballot(kr[u] >= t0));
            c1 += (unsigned)__popcll(__ballot(kr[u] >= t1));
        }
        if (c0 >= (unsigned)(T_SEQ - 204))  kth0 = t0;
        if (c1 >= (unsigned)(T_SEQ - 1944)) kth1 = t1;
    }

    // skip count: base0 = count(k < kth0), cle0 = count(k <= kth0)
    unsigned cge0 = 0u, cgt0 = 0u;
    #pragma unroll
    for (int u = 0; u < 32; ++u) {
        cge0 += (unsigned)__popcll(__ballot(kr[u] >= kth0));
        cgt0 += (unsigned)__popcll(__ballot(kr[u] > kth0));
    }
    const unsigned base0 = (unsigned)T_SEQ - cge0;
    const unsigned cle0  = (unsigned)T_SEQ - cgt0;
    const unsigned scnt = (cle0 > 205u) ? base0 : cle0;
    const float m = k2f(mx);

    // ---- compaction into LDS list: crit <=> k > kth1; unnorm w; z accum ----
    float z = 0.f;
    unsigned bcnt = 0;
    const unsigned long long pm = (lane == 0) ? 0ull : (~0ull >> (64 - lane));
    #pragma unroll
    for (int u8 = 0; u8 < 8; ++u8) {
        #pragma unroll
        for (int q = 0; q < 4; ++q) {
            unsigned k = kr[u8 * 4 + q];
            bool crit = k > kth1;
            unsigned long long bal = __ballot(crit);
            if (crit) {
                float sv = k2f(k);
                float w = __expf(sv - m);
                z += w;
                unsigned pos = bcnt + (unsigned)__popcll(bal & pm);
                if (pos < CAP) {
                    unsigned j = (unsigned)(4 * lane + 256 * u8 + q);
                    list[pos] = make_float2(w, __uint_as_float(j));
                }
            }
            bcnt += (unsigned)__popcll(bal);
        }
    }
    #pragma unroll
    for (int off = 32; off > 0; off >>= 1)
        z += __shfl_xor(z, off);
    const float invz = (z > 0.f) ? (1.f / z) : 0.f;

    // ---- fused gather, 8 independent accumulators (deep memory-level parallelism) ----
    const float* vbl = vh + (size_t)h * T_SEQ * HD + lane;
    const int cnt = (int)min(bcnt, (unsigned)CAP);
    float av[8];
    #pragma unroll
    for (int q = 0; q < 8; ++q) av[q] = 0.f;
    int i = 0;
    for (; i + 8 <= cnt; i += 8) {
        float2 e[8];
        #pragma unroll
        for (int q = 0; q < 8; ++q) e[q] = list[i + q];     // LDS broadcast
        float vv[8];
        #pragma unroll
        for (int q = 0; q < 8; ++q)                          // 8 loads in flight
            vv[q] = vbl[(size_t)__float_as_uint(e[q].y) * HD];
        #pragma unroll
        for (int q = 0; q < 8; ++q)
            av[q] = fmaf(e[q].x, vv[q], av[q]);
    }
    for (; i < cnt; ++i) {
        float2 e = list[i];
        av[0] = fmaf(e.x, vbl[(size_t)__float_as_uint(e.y) * HD], av[0]);
    }
    float acc = ((av[0] + av[1]) + (av[2] + av[3])) + ((av[4] + av[5]) + (av[6] + av[7]));
    att[(size_t)t * D_MODEL + h * HD + lane] = acc * invz;   // first writer of att
    if (lane == 0) {
        unsigned mc = (unsigned)T_SEQ - bcnt - scnt;
        marg[(size_t)h * T_SEQ + t] = (float)mc * (1.f / (float)T_SEQ);
    }
}

// ---------------- K3: per-chunk sums A_c = sum kf x v, b_c = sum kf ----------------
// grid (NCH, 8), block 256
__global__ __launch_bounds__(256) void chunk_sums_kernel(
    const float* __restrict__ kf, const float* __restrict__ vh,
    float* __restrict__ Ac, float* __restrict__ bc)
{
    const int c = blockIdx.x, h = blockIdx.y;
    const int tid = threadIdx.x;
    __shared__ float kfl[CSZ][HD];
    __shared__ float vl[CSZ][HD];
    const size_t base = ((size_t)h * T_SEQ + c * CSZ) * HD;

    for (int l = 0; l < 4; ++l) {
        int p = tid + l * 256;            // float4 index over 64x16
        int row = p >> 4, c4 = (p & 15) * 4;
        *(float4*)&kfl[row][c4] = *(const float4*)(kf + base + (size_t)row * HD + c4);
        *(float4*)&vl[row][c4]  = *(const float4*)(vh + base + (size_t)row * HD + c4);
    }
    __syncthreads();

    const int d = tid >> 2, e0 = (tid & 3) * 16;
    float acc[16] = {};
    for (int u = 0; u < CSZ; ++u) {
        float a = kfl[u][d];
        #pragma unroll
        for (int i = 0; i < 16; ++i) acc[i] = fmaf(a, vl[u][e0 + i], acc[i]);
    }
    float* Adst = Ac + (((size_t)(h * NCH + c) * HD + d) * HD + e0);
    #pragma unroll
    for (int i = 0; i < 16; ++i) Adst[i] = acc[i];

    if (tid < HD) {
        float sum = 0.f;
        for (int u = 0; u < CSZ; ++u) sum += kfl[u][tid];
        bc[(size_t)(h * NCH + c) * HD + tid] = sum;
    }
}

// ---------------- K5: intra-chunk causal linear attention + inline chunk prefix; att += ----------------
// grid (NCH, 8), block 256. The exclusive prefix over chunk states (old prefix_kernel)
// is register-accumulated here from Ac/bc (same ascending-cc order -> bit-identical).
__global__ __launch_bounds__(256) void lin_combine_kernel(
    const float* __restrict__ qf, const float* __restrict__ kf, const float* __restrict__ vh,
    const float* __restrict__ Ac, const float* __restrict__ bc,
    const float* __restrict__ marg, float* __restrict__ att)
{
    const int c = blockIdx.x, h = blockIdx.y;
    const int tid = threadIdx.x;
    __shared__ float Qs[CSZ][65];
    __shared__ float Ks[CSZ][65];   // holds kf for P, then overwritten with Ss
    __shared__ float P[CSZ][66];
    __shared__ float svv[HD];
    __shared__ float coef[CSZ];

    const size_t base = ((size_t)h * T_SEQ + c * CSZ) * HD;
    for (int l = 0; l < 4; ++l) {
        int p = tid + l * 256;
        int row = p >> 4, c4 = (p & 15) * 4;
        *(float4*)&Qs[row][c4] = *(const float4*)(qf + base + (size_t)row * HD + c4);
        *(float4*)&Ks[row][c4] = *(const float4*)(kf + base + (size_t)row * HD + c4);
    }

    // register prefix accumulation over chunks cc < c (exclusive), ascending order
    float4 sA[4];
    #pragma unroll
    for (int l = 0; l < 4; ++l) sA[l] = make_float4(0.f, 0.f, 0.f, 0.f);
    float sb = 0.f;
    {
        const float* Abase = Ac + (size_t)(h * NCH) * 4096;
        for (int cc = 0; cc < c; ++cc) {
            const float* a = Abase + (size_t)cc * 4096;
            #pragma unroll
            for (int l = 0; l < 4; ++l) {
                float4 v = *(const float4*)(a + 4 * (tid + l * 256));
                sA[l].x += v.x; sA[l].y += v.y; sA[l].z += v.z; sA[l].w += v.w;
            }
            if (tid < HD) sb += bc[(size_t)(h * NCH + cc) * HD + tid];
        }
    }
    __syncthreads();

    // P[t][u] = qf_t . kf_u  (zero above diagonal)
    {
        const int tq = tid >> 2, u0 = (tid & 3) * 16;
        float pr[16];
        #pragma unroll
        for (int i = 0; i < 16; ++i) pr[i] = 0.f;
        for (int d = 0; d < HD; ++d) {
            float qv = Qs[tq][d];
            #pragma unroll
            for (int i = 0; i < 16; ++i) pr[i] = fmaf(qv, Ks[u0 + i][d], pr[i]);
        }
        #pragma unroll
        for (int i = 0; i < 16; ++i) P[tq][u0 + i] = (u0 + i <= tq) ? pr[i] : 0.f;
    }
    __syncthreads();

    // overwrite Ks with Ss (register prefix), publish svv; den+coef (wave-0 local)
    #pragma unroll
    for (int l = 0; l < 4; ++l) {
        int p = tid + l * 256;
        int row = p >> 4, c4 = (p & 15) * 4;
        *(float4*)&Ks[row][c4] = sA[l];
    }
    if (tid < HD) svv[tid] = sb;   // wave 0: program-order write before read below
    if (tid < CSZ) {
        const int tq = tid;
        float den = 0.f;
        for (int d = 0; d < HD; ++d) den += Qs[tq][d] * svv[d];
        for (int u = 0; u <= tq; ++u) den += P[tq][u];
        den = fmaxf(den, 1e-6f);
        coef[tq] = marg[(size_t)h * T_SEQ + c * CSZ + tq] / den;
    }
    __syncthreads();

    // lin_num = qf @ Ss + P @ v ; att += scaled
    {
        const int tq = tid >> 2, e0 = (tid & 3) * 16;
        float acc[16];
        #pragma unroll
        for (int i = 0; i < 16; ++i) acc[i] = 0.f;
        for (int d = 0; d < HD; ++d) {
            float qv = Qs[tq][d];
            #pragma unroll
            for (int i = 0; i < 16; ++i) acc[i] = fmaf(qv, Ks[d][e0 + i], acc[i]);
        }
        const float* vb = vh + base;
        for (int u = 0; u <= tq; ++u) {
            float pv = P[tq][u];
            #pragma unroll
            for (int i = 0; i < 16; ++i) acc[i] = fmaf(pv, vb[(size_t)u * HD + e0 + i], acc[i]);
        }
        const float cf = coef[tq];
        float* dst = att + (size_t)(c * CSZ + tq) * D_MODEL + h * HD + e0;
        #pragma unroll
        for (int i = 0; i < 16; ++i) dst[i] += acc[i] * cf;
    }
}

extern "C" void kernel_launch(void* const* d_in, const int* in_sizes, int n_in,
                              void* d_out, int out_size, void* d_ws, size_t ws_size,
                              hipStream_t stream)
{
    const float* x  = (const float*)d_in[0];
    const float* wq = (const float*)d_in[1];
    const float* bq = (const float*)d_in[2];
    const float* wk = (const float*)d_in[3];
    const float* bk = (const float*)d_in[4];
    const float* wv = (const float*)d_in[5];
    const float* bv = (const float*)d_in[6];
    const float* wo = (const float*)d_in[7];
    const float* bo = (const float*)d_in[8];
    float* out = (float*)d_out;

    float* ws = (float*)d_ws;
    const size_t NTD = (size_t)T_SEQ * D_MODEL;         // 1M floats
    const size_t NSS = (size_t)H_HEADS * T_SEQ * T_SEQ; // 33.5M floats (134 MB)
    float* S    = ws;
    float* qh   = S + NSS;
    float* kh   = qh + NTD;
    float* vh   = kh + NTD;
    float* qf   = vh + NTD;
    float* kf   = qf + NTD;
    float* att  = kf + NTD;
    float* Ac   = att + NTD;                // 8*32*4096 = 1M floats
    float* bc   = Ac + NTD;                 // 16384
    float* marg = bc + 16384;               // 16384

    dim3 b256(256);
    proj_qkv_kernel<<<dim3(32, 8, 3), b256, 0, stream>>>(x, wq, bq, wk, bk, wv, bv,
                                                         qh, kh, vh, qf, kf);
    chunk_sums_kernel<<<dim3(NCH, H_HEADS), b256, 0, stream>>>(kf, vh, Ac, bc);
    qk_gemm_kernel<<<dim3(32, 16, 8), b256, 0, stream>>>(qh, kh, S);
    select_kernel<<<dim3(T_SEQ, H_HEADS), dim3(64), 0, stream>>>(S, vh, att, marg);
    lin_combine_kernel<<<dim3(NCH, H_HEADS), b256, 0, stream>>>(qf, kf, vh, Ac, bc, marg, att);
    out_proj_kernel<<<dim3(32, 8), b256, 0, stream>>>(att, wo, bo, out);
}

// Round 18
// 282.319 us; speedup vs baseline: 1.2221x; 1.2221x over previous
//
#include <hip/hip_runtime.h>
#include <math.h>

#define T_SEQ 2048
#define D_MODEL 512
#define H_HEADS 8
#define HD 64
#define NCH 32      // number of chunks
#define CSZ 64      // chunk size  (NCH*CSZ == T_SEQ)
#define CAP 192     // max gathered critical entries per row (generic count = 103)

// order-preserving float<->u32 key transforms
__device__ __forceinline__ unsigned f2k(float f) {
    unsigned u = __float_as_uint(f);
    return (u & 0x80000000u) ? ~u : (u | 0x80000000u);
}
__device__ __forceinline__ float k2f(unsigned k) {
    unsigned u = (k & 0x80000000u) ? (k & 0x7fffffffu) : ~k;
    return __uint_as_float(u);
}

// locate rank rr within a 256-bin wave histogram; each lane holds counts cc[0..3]
// for bins lane*4..lane*4+3 and exclusive lane prefix e0. Wave-uniform outputs.
__device__ __forceinline__ void locate_rank(unsigned rr, unsigned e0,
    const unsigned cc[4], int lane, unsigned& sel_bin, unsigned& sel_nb, unsigned& sel_cnt)
{
    unsigned e1 = e0 + cc[0], e2 = e1 + cc[1], e3 = e2 + cc[2];
    int bin = -1; unsigned nb = 0u, ct = 0u;
    if (rr >= e0 && rr < e1)              { bin = lane * 4 + 0; nb = e0; ct = cc[0]; }
    else if (rr >= e1 && rr < e2)         { bin = lane * 4 + 1; nb = e1; ct = cc[1]; }
    else if (rr >= e2 && rr < e3)         { bin = lane * 4 + 2; nb = e2; ct = cc[2]; }
    else if (rr >= e3 && rr < e3 + cc[3]) { bin = lane * 4 + 3; nb = e3; ct = cc[3]; }
    unsigned long long bal = __ballot(bin >= 0);
    int src = __ffsll((unsigned long long)bal) - 1;
    sel_bin = (unsigned)__shfl(bin, src);
    sel_nb  = (unsigned)__shfl((int)nb, src);
    sel_cnt = (unsigned)__shfl((int)ct, src);
}

// ---------------- K1: QKV projection (x @ W.T + b), head-major store + phi ----------------
// grid (32, 8, 3), block 256. Transposed LDS: As[kk][row], stride 68 (16B-aligned b128 reads).
__global__ __launch_bounds__(256) void proj_qkv_kernel(
    const float* __restrict__ x,
    const float* __restrict__ wq, const float* __restrict__ bq,
    const float* __restrict__ wk, const float* __restrict__ bk,
    const float* __restrict__ wv, const float* __restrict__ bv,
    float* __restrict__ qh, float* __restrict__ kh, float* __restrict__ vh,
    float* __restrict__ qf, float* __restrict__ kf)
{
    const int which = blockIdx.z;
    const float* W    = (which == 0) ? wq : (which == 1) ? wk : wv;
    const float* bias = (which == 0) ? bq : (which == 1) ? bk : bv;
    float* outh = (which == 0) ? qh : (which == 1) ? kh : vh;
    float* outf = (which == 0) ? qf : (which == 1) ? kf : nullptr;

    __shared__ float As[32][68];
    __shared__ float Bs[32][68];
    const int tid = threadIdx.x;
    const int m0 = blockIdx.x * 64;
    const int n0 = blockIdx.y * 64;
    const int rb = (tid >> 4) * 4;
    const int cb = (tid & 15) * 4;

    float acc[4][4] = {};
    for (int k0 = 0; k0 < D_MODEL; k0 += 32) {
        for (int l = 0; l < 2; ++l) {
            int p = tid + l * 256;          // 0..511 float4 slots (64 rows x 8)
            int row = p >> 3;
            int c4 = (p & 7) * 4;
            float4 av = *(const float4*)(x + (size_t)(m0 + row) * D_MODEL + k0 + c4);
            As[c4 + 0][row] = av.x; As[c4 + 1][row] = av.y;
            As[c4 + 2][row] = av.z; As[c4 + 3][row] = av.w;
            float4 wv4 = *(const float4*)(W + (size_t)(n0 + row) * D_MODEL + k0 + c4);
            Bs[c4 + 0][row] = wv4.x; Bs[c4 + 1][row] = wv4.y;
            Bs[c4 + 2][row] = wv4.z; Bs[c4 + 3][row] = wv4.w;
        }
        __syncthreads();
        #pragma unroll
        for (int kk = 0; kk < 32; ++kk) {
            float4 ar = *(const float4*)&As[kk][rb];
            float4 br = *(const float4*)&Bs[kk][cb];
            float arr[4] = {ar.x, ar.y, ar.z, ar.w};
            float brr[4] = {br.x, br.y, br.z, br.w};
            #pragma unroll
            for (int i = 0; i < 4; ++i)
                #pragma unroll
                for (int j = 0; j < 4; ++j)
                    acc[i][j] = fmaf(arr[i], brr[j], acc[i][j]);
        }
        __syncthreads();
    }
    #pragma unroll
    for (int i = 0; i < 4; ++i) {
        int m = m0 + rb + i;
        #pragma unroll
        for (int j = 0; j < 4; ++j) {
            int n = n0 + cb + j;
            float v = acc[i][j] + bias[n];
            int h = n >> 6, d = n & 63;
            size_t idx = ((size_t)(h * T_SEQ) + m) * HD + d;
            outh[idx] = v;
            if (outf) outf[idx] = (v > 0.f) ? (v + 1.f) : expf(v);  // elu+1
        }
    }
}

// ---------------- K6: output projection (att @ wo.T + bo) ----------------
// grid (32, 8), block 256. Transposed LDS.
__global__ __launch_bounds__(256) void out_proj_kernel(
    const float* __restrict__ att, const float* __restrict__ wo,
    const float* __restrict__ bo, float* __restrict__ out)
{
    __shared__ float As[32][68];
    __shared__ float Bs[32][68];
    const int tid = threadIdx.x;
    const int m0 = blockIdx.x * 64;
    const int n0 = blockIdx.y * 64;
    const int rb = (tid >> 4) * 4;
    const int cb = (tid & 15) * 4;

    float acc[4][4] = {};
    for (int k0 = 0; k0 < D_MODEL; k0 += 32) {
        for (int l = 0; l < 2; ++l) {
            int p = tid + l * 256;
            int row = p >> 3;
            int c4 = (p & 7) * 4;
            float4 av = *(const float4*)(att + (size_t)(m0 + row) * D_MODEL + k0 + c4);
            As[c4 + 0][row] = av.x; As[c4 + 1][row] = av.y;
            As[c4 + 2][row] = av.z; As[c4 + 3][row] = av.w;
            float4 wv4 = *(const float4*)(wo + (size_t)(n0 + row) * D_MODEL + k0 + c4);
            Bs[c4 + 0][row] = wv4.x; Bs[c4 + 1][row] = wv4.y;
            Bs[c4 + 2][row] = wv4.z; Bs[c4 + 3][row] = wv4.w;
        }
        __syncthreads();
        #pragma unroll
        for (int kk = 0; kk < 32; ++kk) {
            float4 ar = *(const float4*)&As[kk][rb];
            float4 br = *(const float4*)&Bs[kk][cb];
            float arr[4] = {ar.x, ar.y, ar.z, ar.w};
            float brr[4] = {br.x, br.y, br.z, br.w};
            #pragma unroll
            for (int i = 0; i < 4; ++i)
                #pragma unroll
                for (int j = 0; j < 4; ++j)
                    acc[i][j] = fmaf(arr[i], brr[j], acc[i][j]);
        }
        __syncthreads();
    }
    #pragma unroll
    for (int i = 0; i < 4; ++i) {
        int m = m0 + rb + i;
        #pragma unroll
        for (int j = 0; j < 4; ++j) {
            int n = n0 + cb + j;
            out[(size_t)m * D_MODEL + n] = acc[i][j] + bo[n];
        }
    }
}

// ---------------- K2a: S = Q K^T / 8, per head, 128x64 tiles ----------------
// grid (32 jtile, 16 ttile, 8 head), block 256. Transposed LDS, 8x4 acc/thread.
__global__ __launch_bounds__(256) void qk_gemm_kernel(
    const float* __restrict__ qh, const float* __restrict__ kh, float* __restrict__ S)
{
    __shared__ float As[64][132];  // As[kk][t-row 0..127]
    __shared__ float Bs[64][68];   // Bs[kk][j-col 0..63]
    const int tid = threadIdx.x;
    const int n0 = blockIdx.x * 64;    // key index j
    const int m0 = blockIdx.y * 128;   // query index t
    const int h  = blockIdx.z;
    const float* qb = qh + (size_t)h * T_SEQ * HD;
    const float* kb = kh + (size_t)h * T_SEQ * HD;

    #pragma unroll
    for (int l = 0; l < 8; ++l) {
        int p = tid + l * 256;            // 2048 float4 = 128 rows x 16
        int row = p >> 4, c4 = (p & 15) * 4;
        float4 a = *(const float4*)(qb + (size_t)(m0 + row) * HD + c4);
        As[c4 + 0][row] = a.x; As[c4 + 1][row] = a.y;
        As[c4 + 2][row] = a.z; As[c4 + 3][row] = a.w;
    }
    #pragma unroll
    for (int l = 0; l < 4; ++l) {
        int p = tid + l * 256;            // 1024 float4 = 64 rows x 16
        int row = p >> 4, c4 = (p & 15) * 4;
        float4 b = *(const float4*)(kb + (size_t)(n0 + row) * HD + c4);
        Bs[c4 + 0][row] = b.x; Bs[c4 + 1][row] = b.y;
        Bs[c4 + 2][row] = b.z; Bs[c4 + 3][row] = b.w;
    }
    __syncthreads();

    const int rb = (tid >> 4) * 8;
    const int cb = (tid & 15) * 4;
    float acc[8][4] = {};
    #pragma unroll 8
    for (int kk = 0; kk < HD; ++kk) {
        float4 a0 = *(const float4*)&As[kk][rb];
        float4 a1 = *(const float4*)&As[kk][rb + 4];
        float4 br = *(const float4*)&Bs[kk][cb];
        float arr[8] = {a0.x, a0.y, a0.z, a0.w, a1.x, a1.y, a1.z, a1.w};
        float brr[4] = {br.x, br.y, br.z, br.w};
        #pragma unroll
        for (int i = 0; i < 8; ++i)
            #pragma unroll
            for (int j = 0; j < 4; ++j)
                acc[i][j] = fmaf(arr[i], brr[j], acc[i][j]);
    }
    #pragma unroll
    for (int i = 0; i < 8; ++i) {
        float4 o;
        o.x = acc[i][0] * 0.125f; o.y = acc[i][1] * 0.125f;
        o.z = acc[i][2] * 0.125f; o.w = acc[i][3] * 0.125f;
        *(float4*)(S + ((size_t)h * T_SEQ + m0 + rb + i) * T_SEQ + n0 + cb) = o;
    }
}

// ---------------- K2b: quantile select + FUSED critical gather; WRITES att ----------------
// grid (T_SEQ/4, 8), block 256; wave w handles row blockIdx.x*4 + w.
// Radix-select ranks {204, 1944} with early exit. NO key recovery: critical test is
// prefix-space exact: k > kth1944 <=> (k>>rsh1) > pfx1. cle0 = base0+fct0 from radix
// metadata. Compaction writes (w,j) pairs into the dead histogram LDS, then the wave
// gathers V with 8 independent accumulators (deep MLP). att written with "=".
__global__ __launch_bounds__(256) void select_kernel(
    const float* __restrict__ S, const float* __restrict__ vh,
    float* __restrict__ att, float* __restrict__ marg)
{
    const int h = blockIdx.y;
    const int r = threadIdx.x >> 6;
    const int lane = threadIdx.x & 63;
    const int t = blockIdx.x * 4 + r;
    __shared__ unsigned hists[4][2][256];

    const float* srow = S + ((size_t)h * T_SEQ + t) * T_SEQ;
    unsigned kr[32];
    unsigned mx = 0u;
    #pragma unroll
    for (int u = 0; u < 8; ++u) {
        float4 f = *(const float4*)(srow + (size_t)(lane + u * 64) * 4);
        kr[u * 4 + 0] = f2k(f.x); kr[u * 4 + 1] = f2k(f.y);
        kr[u * 4 + 2] = f2k(f.z); kr[u * 4 + 3] = f2k(f.w);
        mx = max(mx, max(max(kr[u * 4 + 0], kr[u * 4 + 1]), max(kr[u * 4 + 2], kr[u * 4 + 3])));
    }
    #pragma unroll
    for (int off = 32; off > 0; off >>= 1)
        mx = max(mx, (unsigned)__shfl_xor(mx, off));

    unsigned pfx0, pfx1, base0 = 0u, base1 = 0u, fct0 = 0u;
    bool res0 = false, res1 = false;
    unsigned rsh1 = 0u;

    // ---- pass 0: top byte, single shared histogram ----
    {
        uint4 z4 = make_uint4(0u, 0u, 0u, 0u);
        uint4* hv = (uint4*)hists[r];          // 512 u32 = 128 uint4
        hv[lane * 2 + 0] = z4; hv[lane * 2 + 1] = z4;
        #pragma unroll
        for (int u = 0; u < 32; ++u)
            atomicAdd(&hists[r][0][kr[u] >> 24], 1u);
        uint4 a = ((const uint4*)hists[r][0])[lane];
        unsigned cc[4] = {a.x, a.y, a.z, a.w};
        unsigned lsum = cc[0] + cc[1] + cc[2] + cc[3];
        unsigned incl = lsum;
        #pragma unroll
        for (int off = 1; off < 64; off <<= 1) {
            unsigned tv = __shfl_up(incl, off);
            if (lane >= off) incl += tv;
        }
        unsigned e0 = incl - lsum;
        unsigned bin, nb, ct;
        locate_rank(204u, e0, cc, lane, bin, nb, ct);
        pfx0 = bin; base0 = nb; fct0 = ct;
        if (ct == 1u) res0 = true;
        locate_rank(1944u, e0, cc, lane, bin, nb, ct);
        pfx1 = bin; base1 = nb;
        if (ct == 1u) { res1 = true; rsh1 = 24u; }
    }

    // ---- passes 1-3: filtered histograms for unresolved ranks ----
    for (int p = 1; p < 4; ++p) {
        if (res0 && res1) break;
        const int sh = 24 - 8 * p;
        const bool a0 = !res0, a1 = !res1;
        const bool dup = a0 && a1 && (pfx0 == pfx1);
        uint4 z4 = make_uint4(0u, 0u, 0u, 0u);
        uint4* hv = (uint4*)hists[r];
        hv[lane * 2 + 0] = z4; hv[lane * 2 + 1] = z4;
        #pragma unroll
        for (int u = 0; u < 32; ++u) {
            unsigned k = kr[u];
            unsigned hi = k >> (sh + 8);
            unsigned bin = (k >> sh) & 255u;
            if (a0 && hi == pfx0) atomicAdd(&hists[r][0][bin], 1u);
            if (a1 && !dup && hi == pfx1) atomicAdd(&hists[r][1][bin], 1u);
        }
        unsigned cc0[4], e00 = 0u;
        if (a0 || dup) {
            uint4 a = ((const uint4*)hists[r][0])[lane];
            cc0[0] = a.x; cc0[1] = a.y; cc0[2] = a.z; cc0[3] = a.w;
            unsigned lsum = cc0[0] + cc0[1] + cc0[2] + cc0[3];
            unsigned incl = lsum;
            #pragma unroll
            for (int off = 1; off < 64; off <<= 1) {
                unsigned tv = __shfl_up(incl, off);
                if (lane >= off) incl += tv;
            }
            e00 = incl - lsum;
        }
        if (a0) {
            unsigned bin, nb, ct;
            locate_rank(204u - base0, e00, cc0, lane, bin, nb, ct);
            pfx0 = (pfx0 << 8) | bin; base0 += nb; fct0 = ct;
            if (ct == 1u && p < 3) res0 = true;
        }
        if (a1) {
            unsigned bin, nb, ct;
            if (dup) {
                locate_rank(1944u - base1, e00, cc0, lane, bin, nb, ct);
            } else {
                uint4 b = ((const uint4*)hists[r][1])[lane];
                unsigned cc1[4] = {b.x, b.y, b.z, b.w};
                unsigned lsum = cc1[0] + cc1[1] + cc1[2] + cc1[3];
                unsigned incl = lsum;
                #pragma unroll
                for (int off = 1; off < 64; off <<= 1) {
                    unsigned tv = __shfl_up(incl, off);
                    if (lane >= off) incl += tv;
                }
                unsigned e10 = incl - lsum;
                locate_rank(1944u - base1, e10, cc1, lane, bin, nb, ct);
            }
            pfx1 = (pfx1 << 8) | bin; base1 += nb;
            if (ct == 1u && p < 3) { res1 = true; rsh1 = (unsigned)sh; }
        }
    }

    // skip count from radix metadata: cle0 = base0 + count(k==kth0)
    const unsigned cle0 = base0 + fct0;
    const unsigned scnt = (cle0 > 205u) ? base0 : cle0;
    const float m = k2f(mx);

    // ---- compaction into LDS list: crit <=> (k>>rsh1) > pfx1; unnorm w; z accum ----
    float2* list = (float2*)hists[r];     // 2KB/wave >= CAP*8B; hist dead now
    float z = 0.f;
    unsigned bcnt = 0;
    const unsigned long long pm = (lane == 0) ? 0ull : (~0ull >> (64 - lane));
    #pragma unroll
    for (int u8 = 0; u8 < 8; ++u8) {
        #pragma unroll
        for (int q = 0; q < 4; ++q) {
            unsigned k = kr[u8 * 4 + q];
            bool crit = (k >> rsh1) > pfx1;
            unsigned long long bal = __ballot(crit);
            if (crit) {
                float sv = k2f(k);
                float w = __expf(sv - m);
                z += w;
                unsigned pos = bcnt + (unsigned)__popcll(bal & pm);
                if (pos < CAP) {
                    unsigned j = (unsigned)(4 * lane + 256 * u8 + q);
                    list[pos] = make_float2(w, __uint_as_float(j));
                }
            }
            bcnt += (unsigned)__popcll(bal);
        }
    }
    #pragma unroll
    for (int off = 32; off > 0; off >>= 1)
        z += __shfl_xor(z, off);
    const float invz = (z > 0.f) ? (1.f / z) : 0.f;

    // ---- fused gather, 8 independent accumulators (deep memory-level parallelism) ----
    const float* vbl = vh + (size_t)h * T_SEQ * HD + lane;
    const int cnt = (int)min(bcnt, (unsigned)CAP);
    float av[8];
    #pragma unroll
    for (int q = 0; q < 8; ++q) av[q] = 0.f;
    int i = 0;
    for (; i + 8 <= cnt; i += 8) {
        float2 e[8];
        #pragma unroll
        for (int q = 0; q < 8; ++q) e[q] = list[i + q];     // LDS broadcast
        float vv[8];
        #pragma unroll
        for (int q = 0; q < 8; ++q)                          // 8 loads in flight
            vv[q] = vbl[(size_t)__float_as_uint(e[q].y) * HD];
        #pragma unroll
        for (int q = 0; q < 8; ++q)
            av[q] = fmaf(e[q].x, vv[q], av[q]);
    }
    for (; i < cnt; ++i) {
        float2 e = list[i];
        av[0] = fmaf(e.x, vbl[(size_t)__float_as_uint(e.y) * HD], av[0]);
    }
    float acc = ((av[0] + av[1]) + (av[2] + av[3])) + ((av[4] + av[5]) + (av[6] + av[7]));
    att[(size_t)t * D_MODEL + h * HD + lane] = acc * invz;   // first writer of att
    if (lane == 0) {
        unsigned mc = (unsigned)T_SEQ - bcnt - scnt;
        marg[(size_t)h * T_SEQ + t] = (float)mc * (1.f / (float)T_SEQ);
    }
}

// ---------------- K3: per-chunk sums A_c = sum kf x v, b_c = sum kf ----------------
// grid (NCH, 8), block 256
__global__ __launch_bounds__(256) void chunk_sums_kernel(
    const float* __restrict__ kf, const float* __restrict__ vh,
    float* __restrict__ Ac, float* __restrict__ bc)
{
    const int c = blockIdx.x, h = blockIdx.y;
    const int tid = threadIdx.x;
    __shared__ float kfl[CSZ][HD];
    __shared__ float vl[CSZ][HD];
    const size_t base = ((size_t)h * T_SEQ + c * CSZ) * HD;

    for (int l = 0; l < 4; ++l) {
        int p = tid + l * 256;            // float4 index over 64x16
        int row = p >> 4, c4 = (p & 15) * 4;
        *(float4*)&kfl[row][c4] = *(const float4*)(kf + base + (size_t)row * HD + c4);
        *(float4*)&vl[row][c4]  = *(const float4*)(vh + base + (size_t)row * HD + c4);
    }
    __syncthreads();

    const int d = tid >> 2, e0 = (tid & 3) * 16;
    float acc[16] = {};
    for (int u = 0; u < CSZ; ++u) {
        float a = kfl[u][d];
        #pragma unroll
        for (int i = 0; i < 16; ++i) acc[i] = fmaf(a, vl[u][e0 + i], acc[i]);
    }
    float* Adst = Ac + (((size_t)(h * NCH + c) * HD + d) * HD + e0);
    #pragma unroll
    for (int i = 0; i < 16; ++i) Adst[i] = acc[i];

    if (tid < HD) {
        float sum = 0.f;
        for (int u = 0; u < CSZ; ++u) sum += kfl[u][tid];
        bc[(size_t)(h * NCH + c) * HD + tid] = sum;
    }
}

// ---------------- K5: intra-chunk causal linear attention + inline chunk prefix; att += ----------------
// grid (NCH, 8), block 256. The exclusive prefix over chunk states (old prefix_kernel)
// is register-accumulated here from Ac/bc (same ascending-cc order -> bit-identical).
__global__ __launch_bounds__(256) void lin_combine_kernel(
    const float* __restrict__ qf, const float* __restrict__ kf, const float* __restrict__ vh,
    const float* __restrict__ Ac, const float* __restrict__ bc,
    const float* __restrict__ marg, float* __restrict__ att)
{
    const int c = blockIdx.x, h = blockIdx.y;
    const int tid = threadIdx.x;
    __shared__ float Qs[CSZ][65];
    __shared__ float Ks[CSZ][65];   // holds kf for P, then overwritten with Ss
    __shared__ float P[CSZ][66];
    __shared__ float svv[HD];
    __shared__ float coef[CSZ];

    const size_t base = ((size_t)h * T_SEQ + c * CSZ) * HD;
    for (int l = 0; l < 4; ++l) {
        int p = tid + l * 256;
        int row = p >> 4, c4 = (p & 15) * 4;
        *(float4*)&Qs[row][c4] = *(const float4*)(qf + base + (size_t)row * HD + c4);
        *(float4*)&Ks[row][c4] = *(const float4*)(kf + base + (size_t)row * HD + c4);
    }

    // register prefix accumulation over chunks cc < c (exclusive), ascending order
    float4 sA[4];
    #pragma unroll
    for (int l = 0; l < 4; ++l) sA[l] = make_float4(0.f, 0.f, 0.f, 0.f);
    float sb = 0.f;
    {
        const float* Abase = Ac + (size_t)(h * NCH) * 4096;
        for (int cc = 0; cc < c; ++cc) {
            const float* a = Abase + (size_t)cc * 4096;
            #pragma unroll
            for (int l = 0; l < 4; ++l) {
                float4 v = *(const float4*)(a + 4 * (tid + l * 256));
                sA[l].x += v.x; sA[l].y += v.y; sA[l].z += v.z; sA[l].w += v.w;
            }
            if (tid < HD) sb += bc[(size_t)(h * NCH + cc) * HD + tid];
        }
    }
    __syncthreads();

    // P[t][u] = qf_t . kf_u  (zero above diagonal)
    {
        const int tq = tid >> 2, u0 = (tid & 3) * 16;
        float pr[16];
        #pragma unroll
        for (int i = 0; i < 16; ++i) pr[i] = 0.f;
        for (int d = 0; d < HD; ++d) {
            float qv = Qs[tq][d];
            #pragma unroll
            for (int i = 0; i < 16; ++i) pr[i] = fmaf(qv, Ks[u0 + i][d], pr[i]);
        }
        #pragma unroll
        for (int i = 0; i < 16; ++i) P[tq][u0 + i] = (u0 + i <= tq) ? pr[i] : 0.f;
    }
    __syncthreads();

    // overwrite Ks with Ss (register prefix), publish svv; den+coef (wave-0 local)
    #pragma unroll
    for (int l = 0; l < 4; ++l) {
        int p = tid + l * 256;
        int row = p >> 4, c4 = (p & 15) * 4;
        *(float4*)&Ks[row][c4] = sA[l];
    }
    if (tid < HD) svv[tid] = sb;   // wave 0: program-order write before read below
    if (tid < CSZ) {
        const int tq = tid;
        float den = 0.f;
        for (int d = 0; d < HD; ++d) den += Qs[tq][d] * svv[d];
        for (int u = 0; u <= tq; ++u) den += P[tq][u];
        den = fmaxf(den, 1e-6f);
        coef[tq] = marg[(size_t)h * T_SEQ + c * CSZ + tq] / den;
    }
    __syncthreads();

    // lin_num = qf @ Ss + P @ v ; att += scaled
    {
        const int tq = tid >> 2, e0 = (tid & 3) * 16;
        float acc[16];
        #pragma unroll
        for (int i = 0; i < 16; ++i) acc[i] = 0.f;
        for (int d = 0; d < HD; ++d) {
            float qv = Qs[tq][d];
            #pragma unroll
            for (int i = 0; i < 16; ++i) acc[i] = fmaf(qv, Ks[d][e0 + i], acc[i]);
        }
        const float* vb = vh + base;
        for (int u = 0; u <= tq; ++u) {
            float pv = P[tq][u];
            #pragma unroll
            for (int i = 0; i < 16; ++i) acc[i] = fmaf(pv, vb[(size_t)u * HD + e0 + i], acc[i]);
        }
        const float cf = coef[tq];
        float* dst = att + (size_t)(c * CSZ + tq) * D_MODEL + h * HD + e0;
        #pragma unroll
        for (int i = 0; i < 16; ++i) dst[i] += acc[i] * cf;
    }
}

extern "C" void kernel_launch(void* const* d_in, const int* in_sizes, int n_in,
                              void* d_out, int out_size, void* d_ws, size_t ws_size,
                              hipStream_t stream)
{
    const float* x  = (const float*)d_in[0];
    const float* wq = (const float*)d_in[1];
    const float* bq = (const float*)d_in[2];
    const float* wk = (const float*)d_in[3];
    const float* bk = (const float*)d_in[4];
    const float* wv = (const float*)d_in[5];
    const float* bv = (const float*)d_in[6];
    const float* wo = (const float*)d_in[7];
    const float* bo = (const float*)d_in[8];
    float* out = (float*)d_out;

    float* ws = (float*)d_ws;
    const size_t NTD = (size_t)T_SEQ * D_MODEL;         // 1M floats
    const size_t NSS = (size_t)H_HEADS * T_SEQ * T_SEQ; // 33.5M floats (134 MB)
    float* S    = ws;
    float* qh   = S + NSS;
    float* kh   = qh + NTD;
    float* vh   = kh + NTD;
    float* qf   = vh + NTD;
    float* kf   = qf + NTD;
    float* att  = kf + NTD;
    float* Ac   = att + NTD;                // 8*32*4096 = 1M floats
    float* bc   = Ac + NTD;                 // 16384
    float* marg = bc + 16384;               // 16384

    dim3 b256(256);
    proj_qkv_kernel<<<dim3(32, 8, 3), b256, 0, stream>>>(x, wq, bq, wk, bk, wv, bv,
                                                         qh, kh, vh, qf, kf);
    qk_gemm_kernel<<<dim3(32, 16, 8), b256, 0, stream>>>(qh, kh, S);
    select_kernel<<<dim3(T_SEQ / 4, H_HEADS), b256, 0, stream>>>(S, vh, att, marg);
    chunk_sums_kernel<<<dim3(NCH, H_HEADS), b256, 0, stream>>>(kf, vh, Ac, bc);
    lin_combine_kernel<<<dim3(NCH, H_HEADS), b256, 0, stream>>>(qf, kf, vh, Ac, bc, marg, att);
    out_proj_kernel<<<dim3(32, 8), b256, 0, stream>>>(att, wo, bo, out);
}